// Round 9
// baseline (2473.270 us; speedup 1.0000x reference)
//
#include <hip/hip_runtime.h>
#include <hip/hip_bf16.h>
#include <cstdint>
#include <cstddef>

// Model: B=1024, S=60, CIN=25, D=256, H=256, T=S+2=62
// Inputs fp32, output fp32; internal bf16 activations/weights, fp32 accum.
//
// Round-8 analysis: distance-2 SWP clean (no spill) but per-CU L2 pull stuck
// at ~97 GB/s vs ~135-154 GB/s port ceiling — one wave/SIMD can't keep enough
// loads in flight (in-order vmcnt, ~300cyc L2 latency vs ~150cyc cover).
// Round 9: split-K TLP. 8 waves/WG (2/SIMD): wave (p,half) computes unit-pair
// p over K-half `half`. half-1 writes fp32 partials to LDS (stride-68 pad);
// half-0 merges + cell update. Two barriers/step as before. Per-wave chain
// halves, outstanding loads per SIMD double -> stream at the port ceiling.

typedef __attribute__((ext_vector_type(8))) short short8;
typedef __attribute__((ext_vector_type(4))) float floatx4;

#define BATCH 1024
#define TSTEPS 62

__device__ __forceinline__ float bf2f(short s) {
    union { unsigned u; float f; } v;
    v.u = ((unsigned)(unsigned short)s) << 16;
    return v.f;
}
__device__ __forceinline__ short f2bf(float f) {
    union { float f; unsigned u; } v; v.f = f;
    unsigned r = (v.u + 0x7fffu + ((v.u >> 16) & 1u)) >> 16;  // RNE
    return (short)r;
}
// fast gates: v_exp_f32 + v_rcp_f32; rel err ~1e-6 << bf16 h rounding
__device__ __forceinline__ float sigf(float x) {
    return __builtin_amdgcn_rcpf(1.0f + __expf(-x));
}
__device__ __forceinline__ float tanhf_fast(float x) {
    return 2.0f * __builtin_amdgcn_rcpf(1.0f + __expf(-2.0f * x)) - 1.0f;
}

// ------------- repack into wave-local blocked layout -----------------------
// dst idx = ((((dr*4 + p)*KB + kb)*16 + gs)*64 + lane)*8 + j
// src row = (gs>>2)*256 + p*64 + (gs&3)*16 + (lane&15),
// src k   = kb*32 + (lane>>4)*8 + j   (k<XI: Wih, else Whh[k-XI])
__global__ __launch_bounds__(256) void repack_kernel(
    const float* __restrict__ Wih, const float* __restrict__ Whh,
    short* __restrict__ Wp, int XI)
{
    const int KB = (XI + 256) / 32;
    int idx = blockIdx.x * 256 + threadIdx.x;
    if (idx >= 8 * KB * 8192) return;
    int j    = idx & 7;
    int lane = (idx >> 3) & 63;
    int gs   = (idx >> 9) & 15;
    int rem  = idx >> 13;
    int kb   = rem % KB;
    int rem2 = rem / KB;
    int p    = rem2 & 3;
    int dr   = rem2 >> 2;
    int row  = (gs >> 2) * 256 + p * 64 + (gs & 3) * 16 + (lane & 15);
    int k    = kb * 32 + (lane >> 4) * 8 + j;
    float v = (k < XI) ? Wih[((size_t)dr * 1024 + row) * XI + k]
                       : Whh[((size_t)dr * 1024 + row) * 256 + (k - XI)];
    Wp[idx] = f2bf(v);
}

// ---------------- embed: seq[t][b][d] --------------------------------------
__global__ __launch_bounds__(256) void embed_kernel(
    const float* __restrict__ x, const float* __restrict__ Wg,
    const float* __restrict__ bg, const float* __restrict__ Wl,
    const float* __restrict__ bl, short* __restrict__ seq)
{
    const int b = blockIdx.x;
    const int d = threadIdx.x;  // 256 = D
    __shared__ float xs[1500];
    for (int i = d; i < 1500; i += 256) xs[i] = x[(size_t)b * 1500 + i];
    __syncthreads();

    float g = bg[d];
#pragma unroll
    for (int c = 0; c < 16; ++c) g += xs[9 + c] * Wg[d * 16 + c];
    short gb = f2bf(g);
    seq[((size_t)0 * BATCH + b) * 256 + d] = gb;
    seq[((size_t)61 * BATCH + b) * 256 + d] = gb;

    for (int t = 0; t < 60; ++t) {
        float v = bl[d];
#pragma unroll
        for (int c = 0; c < 9; ++c) v += xs[t * 25 + c] * Wl[d * 9 + c];
        seq[((size_t)(t + 1) * BATCH + b) * 256 + d] = f2bf(v);
    }
}

// ---------------- persistent biLSTM layer ----------------------------------
#define LOADG8(BUF, P, gh)                                                       \
    {                                                                            \
        _Pragma("unroll")                                                        \
        for (int f = 0; f < 8; ++f)                                              \
            BUF[f] = *reinterpret_cast<const short8*>((P) + ((gh) * 8 + f) * 512); \
    }
#define LOADA(DST, kbg)                                                          \
    {                                                                            \
        DST = ((kbg) < XB)                                                       \
            ? *reinterpret_cast<const short8*>(Xrow + (kbg) * 32)                \
            : *reinterpret_cast<const short8*>(&h_lds[lr][((kbg) - XB) * 32 + quad * 8]); \
    }
#define MFMA8(AV, BUF, gh)                                                       \
    {                                                                            \
        _Pragma("unroll")                                                        \
        for (int f = 0; f < 8; ++f)                                              \
            acc[(gh) * 8 + f] = __builtin_amdgcn_mfma_f32_16x16x32_bf16(         \
                AV, BUF[f], acc[(gh) * 8 + f], 0, 0, 0);                         \
    }

template <int KK>  // 512 (layer0: XI=256) or 768 (layer1: XI=512)
__global__ __launch_bounds__(512, 1) void lstm_kernel(
    const short* __restrict__ X,      // (62,1024,XI) bf16 time-major
    const short* __restrict__ Wp,     // blocked weights, see repack_kernel
    const float* __restrict__ bih,    // (2,1024) fp32
    const float* __restrict__ bhh,    // (2,1024) fp32
    short* __restrict__ Hout)         // (62,1024,512); dir d -> cols [256d,..)
{
    constexpr int XI  = KK - 256;
    constexpr int KB  = KK / 32;   // 16 or 24
    constexpr int KB2 = KB / 2;    // 8 or 12 (even)
    constexpr int XB  = XI / 32;   // 8 or 16; note XB >= KB2 (half0 all-global)

    const int wg    = blockIdx.x;     // 128 = 64 tiles x 2 dirs
    const int dir   = wg >> 6;
    const int bbase = (wg & 63) * 16;
    const int tid   = threadIdx.x;    // 512 threads = 8 waves
    const int w8    = tid >> 6;
    const int p     = w8 & 3;         // unit-pair group: units [64p, 64p+64)
    const int half  = w8 >> 2;        // K half
    const int lane  = tid & 63;
    const int quad  = lane >> 4;      // C rows quad*4..+3 ; A k-offset quad*8
    const int lr    = lane & 15;      // A row (batch) / C col

    __shared__ __align__(16) short h_lds[16][264];      // +8 pad
    __shared__ float bias_sh[1024];
    __shared__ __align__(16) float acc_sh[4 * 64 * 68]; // [p][lane][64 +4 pad]

    for (int i = tid; i < 16 * 264; i += 512) (&h_lds[0][0])[i] = 0;
    for (int i = tid; i < 1024; i += 512)
        bias_sh[i] = bih[dir * 1024 + i] + bhh[dir * 1024 + i];

    // wave-local weight base: pair p, K-half `half`
    const short* wpb = Wp + (((size_t)(dir * 4 + p) * KB) << 13) +
                       (size_t)half * KB2 * 8192 + lane * 8;
    const int kbase = half * KB2;
    float* accx = &acc_sh[(p * 64 + lane) * 68];

    float c_st[4][4];  // live only in half-0 waves
#pragma unroll
    for (int s = 0; s < 4; ++s)
#pragma unroll
        for (int r = 0; r < 4; ++r) c_st[s][r] = 0.0f;

    __syncthreads();

    for (int st = 0; st < TSTEPS; ++st) {
        const int t = dir ? (TSTEPS - 1 - st) : st;
        const short* Xrow = X + ((size_t)t * BATCH + bbase + lr) * XI + quad * 8;

        floatx4 acc[16];
#pragma unroll
        for (int i = 0; i < 16; ++i) acc[i] = (floatx4){0.f, 0.f, 0.f, 0.f};

        // distance-2 software pipeline over this wave's KB2 blocks
        short8 X0[8], X1[8], Y0[8], Y1[8], a_cur, a_nxt;
        const short* blk = wpb;
        LOADG8(X0, blk, 0);
        LOADG8(X1, blk, 1);
        LOADA(a_cur, kbase);
#pragma unroll 1
        for (int kb = 0; kb < KB2 - 2; kb += 2) {
            LOADG8(Y0, blk + 8192, 0);
            LOADG8(Y1, blk + 8192, 1);
            LOADA(a_nxt, kbase + kb + 1);
            MFMA8(a_cur, X0, 0);
            MFMA8(a_cur, X1, 1);
            a_cur = a_nxt;
            LOADG8(X0, blk + 2 * 8192, 0);
            LOADG8(X1, blk + 2 * 8192, 1);
            LOADA(a_nxt, kbase + kb + 2);
            MFMA8(a_cur, Y0, 0);
            MFMA8(a_cur, Y1, 1);
            a_cur = a_nxt;
            blk += 2 * 8192;
        }
        // epilogue: last two blocks
        LOADG8(Y0, blk + 8192, 0);
        LOADG8(Y1, blk + 8192, 1);
        LOADA(a_nxt, kbase + KB2 - 1);
        MFMA8(a_cur, X0, 0);
        MFMA8(a_cur, X1, 1);
        a_cur = a_nxt;
        MFMA8(a_cur, Y0, 0);
        MFMA8(a_cur, Y1, 1);

        if (half == 1) {  // deposit partials for the merge
#pragma unroll
            for (int i = 0; i < 16; ++i)
                *reinterpret_cast<floatx4*>(accx + i * 4) = acc[i];
        }
        __syncthreads();  // partials ready; half-1 done reading h_lds

        if (half == 0) {
            // merge partner partials + cell update (i,f,g,o co-located per lane)
#pragma unroll
            for (int s = 0; s < 4; ++s) {
                int j = p * 64 + s * 16 + lr;
                float bi  = bias_sh[0 * 256 + j];
                float bf  = bias_sh[1 * 256 + j];
                float bgv = bias_sh[2 * 256 + j];
                float bo  = bias_sh[3 * 256 + j];
#pragma unroll
                for (int r = 0; r < 4; ++r) {
                    float iv = acc[0 * 4 + s][r] + accx[(0 * 4 + s) * 4 + r] + bi;
                    float fv = acc[1 * 4 + s][r] + accx[(1 * 4 + s) * 4 + r] + bf;
                    float gv = acc[2 * 4 + s][r] + accx[(2 * 4 + s) * 4 + r] + bgv;
                    float ov = acc[3 * 4 + s][r] + accx[(3 * 4 + s) * 4 + r] + bo;
                    float c = sigf(fv) * c_st[s][r] + sigf(iv) * tanhf_fast(gv);
                    c_st[s][r] = c;
                    float h = sigf(ov) * tanhf_fast(c);
                    short hb = f2bf(h);
                    int m = quad * 4 + r;
                    h_lds[m][j] = hb;
                    Hout[((size_t)t * BATCH + bbase + m) * 512 + dir * 256 + j] = hb;
                }
            }
        }
        __syncthreads();  // new h visible; acc_sh free for next step
    }
}

// ---------------- heads (fp32 output) --------------------------------------
__global__ __launch_bounds__(256) void lout_kernel(
    const short* __restrict__ h1, const float* __restrict__ Wlp,
    const float* __restrict__ blp, float* __restrict__ out)
{
    __shared__ float wl[6 * 512];
    for (int i = threadIdx.x; i < 6 * 512; i += 256) wl[i] = Wlp[i];
    __syncthreads();

    int idx = blockIdx.x * 256 + threadIdx.x;
    if (idx >= BATCH * 60) return;
    int b = idx & (BATCH - 1);
    int s = idx >> 10;
    const short* hrow = h1 + ((size_t)(s + 1) * BATCH + b) * 512;

    float acc[6];
#pragma unroll
    for (int j = 0; j < 6; ++j) acc[j] = blp[j];
    for (int k = 0; k < 512; k += 8) {
        short8 hv = *reinterpret_cast<const short8*>(hrow + k);
#pragma unroll
        for (int e = 0; e < 8; ++e) {
            float h = bf2f(hv[e]);
#pragma unroll
            for (int j = 0; j < 6; ++j) acc[j] += h * wl[j * 512 + k + e];
        }
    }
    float* orow = out + ((size_t)b * 60 + s) * 14;
#pragma unroll
    for (int j = 0; j < 6; ++j) orow[j] = acc[j];
}

__global__ __launch_bounds__(256) void gout_kernel(
    const short* __restrict__ h1, const float* __restrict__ Wgp,
    const float* __restrict__ bgp, float* __restrict__ out)
{
    __shared__ float wg[8 * 1024];
    for (int i = threadIdx.x; i < 8 * 1024; i += 256) wg[i] = Wgp[i];
    __syncthreads();

    int b = blockIdx.x * 256 + threadIdx.x;
    if (b >= BATCH) return;
    const short* ha = h1 + (size_t)b * 512;
    const short* hb = h1 + ((size_t)61 * BATCH + b) * 512;

    float acc[8];
#pragma unroll
    for (int j = 0; j < 8; ++j) acc[j] = bgp[j];
    for (int k = 0; k < 512; k += 8) {
        short8 h1v = *reinterpret_cast<const short8*>(ha + k);
        short8 h2v = *reinterpret_cast<const short8*>(hb + k);
#pragma unroll
        for (int e = 0; e < 8; ++e) {
            float v1 = bf2f(h1v[e]);
            float v2 = bf2f(h2v[e]);
#pragma unroll
            for (int j = 0; j < 8; ++j) {
                acc[j] += v1 * wg[j * 1024 + k + e];
                acc[j] += v2 * wg[j * 1024 + 512 + k + e];
            }
        }
    }
    for (int s = 0; s < 60; ++s) {
        float* orow = out + ((size_t)b * 60 + s) * 14 + 6;
#pragma unroll
        for (int j = 0; j < 8; ++j) orow[j] = acc[j];
    }
}

// ---------------- launch ---------------------------------------------------
extern "C" void kernel_launch(void* const* d_in, const int* in_sizes, int n_in,
                              void* d_out, int out_size, void* d_ws, size_t ws_size,
                              hipStream_t stream)
{
    const float* x    = (const float*)d_in[0];
    const float* Wg   = (const float*)d_in[1];
    const float* bg   = (const float*)d_in[2];
    const float* Wl   = (const float*)d_in[3];
    const float* bl   = (const float*)d_in[4];
    const float* Wih0 = (const float*)d_in[5];
    const float* Whh0 = (const float*)d_in[6];
    const float* bih0 = (const float*)d_in[7];
    const float* bhh0 = (const float*)d_in[8];
    const float* Wih1 = (const float*)d_in[9];
    const float* Whh1 = (const float*)d_in[10];
    const float* bih1 = (const float*)d_in[11];
    const float* bhh1 = (const float*)d_in[12];
    const float* Wgp  = (const float*)d_in[13];
    const float* bgp  = (const float*)d_in[14];
    const float* Wlp  = (const float*)d_in[15];
    const float* blp  = (const float*)d_in[16];
    float* out = (float*)d_out;

    const size_t seq_elems = (size_t)TSTEPS * BATCH * 256;   // 16,252,928
    const size_t h_elems   = (size_t)TSTEPS * BATCH * 512;   // 32,505,856
    const int    w0_elems  = 2 * 1024 * 512;                 // 1,048,576
    const int    w1_elems  = 2 * 1024 * 768;                 // 1,572,864

    short* seq = (short*)d_ws;
    short* h0  = seq + seq_elems;
    short* h1  = h0 + h_elems;
    short* wp0 = h1 + h_elems;
    short* wp1 = wp0 + w0_elems;
    const size_t need = (seq_elems + 2 * h_elems + w0_elems + w1_elems) * sizeof(short);
    if (ws_size < need) return;

    repack_kernel<<<(w0_elems + 255) / 256, 256, 0, stream>>>(Wih0, Whh0, wp0, 256);
    repack_kernel<<<(w1_elems + 255) / 256, 256, 0, stream>>>(Wih1, Whh1, wp1, 512);

    embed_kernel<<<BATCH, 256, 0, stream>>>(x, Wg, bg, Wl, bl, seq);
    lstm_kernel<512><<<128, 512, 0, stream>>>(seq, wp0, bih0, bhh0, h0);
    lstm_kernel<768><<<128, 512, 0, stream>>>(h0, wp1, bih1, bhh1, h1);
    lout_kernel<<<(BATCH * 60 + 255) / 256, 256, 0, stream>>>(h1, Wlp, blp, out);
    gout_kernel<<<(BATCH + 255) / 256, 256, 0, stream>>>(h1, Wgp, bgp, out);
}

// Round 10
// 1814.316 us; speedup vs baseline: 1.3632x; 1.3632x over previous
//
#include <hip/hip_runtime.h>
#include <hip/hip_bf16.h>
#include <cstdint>
#include <cstddef>

// Model: B=1024, S=60, CIN=25, D=256, H=256, T=S+2=62
// Inputs fp32, output fp32; internal bf16 activations/weights, fp32 accum.
//
// Round-10 restructure: the input-GEMM part of each LSTM step is recurrence-
// independent. pre = X @ Wih^T is computed for all t by pre_gemm (proper GEMM,
// high occupancy, no barriers) into a bf16 buffer laid out in MFMA C-order;
// lstm_rec then streams only Whh (0.5 MB/step vs 1.5/1.0) and adds pre + bias
// in the epilogue. Round-9 lesson: 512-thread blocks silently halve the VGPR
// budget (VGPR=128, scratch explosion) -> everything stays at 256 threads,
// #pragma unroll 1 loops, named buffers, static indices.
// Fallback: if ws_size < 428 MB, run the round-8 fused path (168 MB).

typedef __attribute__((ext_vector_type(8))) short short8;
typedef __attribute__((ext_vector_type(4))) short short4v;
typedef __attribute__((ext_vector_type(4))) float floatx4;

#define BATCH 1024
#define TSTEPS 62

__device__ __forceinline__ float bf2f(short s) {
    union { unsigned u; float f; } v;
    v.u = ((unsigned)(unsigned short)s) << 16;
    return v.f;
}
__device__ __forceinline__ short f2bf(float f) {
    union { float f; unsigned u; } v; v.f = f;
    unsigned r = (v.u + 0x7fffu + ((v.u >> 16) & 1u)) >> 16;  // RNE
    return (short)r;
}
__device__ __forceinline__ float sigf(float x) {
    return __builtin_amdgcn_rcpf(1.0f + __expf(-x));
}
__device__ __forceinline__ float tanhf_fast(float x) {
    return 2.0f * __builtin_amdgcn_rcpf(1.0f + __expf(-2.0f * x)) - 1.0f;
}

// shared fragment macros (acc[16] in scope)
#define LOADG8(BUF, P, gh)                                                       \
    {                                                                            \
        _Pragma("unroll")                                                        \
        for (int f = 0; f < 8; ++f)                                              \
            BUF[f] = *reinterpret_cast<const short8*>((P) + ((gh) * 8 + f) * 512); \
    }
#define MFMA8(AV, BUF, gh)                                                       \
    {                                                                            \
        _Pragma("unroll")                                                        \
        for (int f = 0; f < 8; ++f)                                              \
            acc[(gh) * 8 + f] = __builtin_amdgcn_mfma_f32_16x16x32_bf16(         \
                AV, BUF[f], acc[(gh) * 8 + f], 0, 0, 0);                         \
    }

// ------------- repack concat [Wih|Whh] (XI=0 -> Whh-only, KB=8) -------------
// dst idx = ((((dr*4 + p)*KB + kb)*16 + gs)*64 + lane)*8 + j
__global__ __launch_bounds__(256) void repack_kernel(
    const float* __restrict__ Wih, const float* __restrict__ Whh,
    short* __restrict__ Wp, int XI)
{
    const int KB = (XI + 256) / 32;
    int idx = blockIdx.x * 256 + threadIdx.x;
    if (idx >= 8 * KB * 8192) return;
    int j    = idx & 7;
    int lane = (idx >> 3) & 63;
    int gs   = (idx >> 9) & 15;
    int rem  = idx >> 13;
    int kb   = rem % KB;
    int rem2 = rem / KB;
    int p    = rem2 & 3;
    int dr   = rem2 >> 2;
    int row  = (gs >> 2) * 256 + p * 64 + (gs & 3) * 16 + (lane & 15);
    int k    = kb * 32 + (lane >> 4) * 8 + j;
    float v = (k < XI) ? Wih[((size_t)dr * 1024 + row) * XI + k]
                       : Whh[((size_t)dr * 1024 + row) * 256 + (k - XI)];
    Wp[idx] = f2bf(v);
}

// ------------- repack Wih-only blocked (for pre_gemm) ----------------------
__global__ __launch_bounds__(256) void repack_a_kernel(
    const float* __restrict__ Wih, short* __restrict__ Wp, int XI)
{
    const int KB = XI / 32;
    int idx = blockIdx.x * 256 + threadIdx.x;
    if (idx >= 8 * KB * 8192) return;
    int j    = idx & 7;
    int lane = (idx >> 3) & 63;
    int gs   = (idx >> 9) & 15;
    int rem  = idx >> 13;
    int kb   = rem % KB;
    int rem2 = rem / KB;
    int p    = rem2 & 3;
    int dr   = rem2 >> 2;
    int row  = (gs >> 2) * 256 + p * 64 + (gs & 3) * 16 + (lane & 15);
    int k    = kb * 32 + (lane >> 4) * 8 + j;
    Wp[idx] = f2bf(Wih[((size_t)dr * 1024 + row) * XI + k]);
}

// ---------------- embed: seq[t][b][d] --------------------------------------
__global__ __launch_bounds__(256) void embed_kernel(
    const float* __restrict__ x, const float* __restrict__ Wg,
    const float* __restrict__ bg, const float* __restrict__ Wl,
    const float* __restrict__ bl, short* __restrict__ seq)
{
    const int b = blockIdx.x;
    const int d = threadIdx.x;  // 256 = D
    __shared__ float xs[1500];
    for (int i = d; i < 1500; i += 256) xs[i] = x[(size_t)b * 1500 + i];
    __syncthreads();

    float g = bg[d];
#pragma unroll
    for (int c = 0; c < 16; ++c) g += xs[9 + c] * Wg[d * 16 + c];
    short gb = f2bf(g);
    seq[((size_t)0 * BATCH + b) * 256 + d] = gb;
    seq[((size_t)61 * BATCH + b) * 256 + d] = gb;

    for (int t = 0; t < 60; ++t) {
        float v = bl[d];
#pragma unroll
        for (int c = 0; c < 9; ++c) v += xs[t * 25 + c] * Wl[d * 9 + c];
        seq[((size_t)(t + 1) * BATCH + b) * 256 + d] = f2bf(v);
    }
}

// ---------------- pre_gemm: Pre[t][dir][tile][j1024][m16] = X@Wih^T --------
template <int XI>  // 256 (layer0) or 512 (layer1)
__global__ __launch_bounds__(256, 1) void pre_gemm_kernel(
    const short* __restrict__ X,    // (62,1024,XI) bf16
    const short* __restrict__ Wa,   // blocked, repack_a
    short* __restrict__ Pre)
{
    constexpr int XB = XI / 32;     // 8 or 16 (even)
    const int wg   = blockIdx.x;    // 62*128
    const int t    = wg >> 7;
    const int dir  = (wg >> 6) & 1;
    const int tile = wg & 63;
    const int tid  = threadIdx.x;
    const int p    = tid >> 6;
    const int lane = tid & 63;
    const int quad = lane >> 4;
    const int lr   = lane & 15;

    const short* wpb  = Wa + (((size_t)(dir * 4 + p) * XB) << 13) + lane * 8;
    const short* Xrow = X + ((size_t)t * BATCH + tile * 16 + lr) * XI + quad * 8;

    floatx4 acc[16];
#pragma unroll
    for (int i = 0; i < 16; ++i) acc[i] = (floatx4){0.f, 0.f, 0.f, 0.f};

    short8 X0[8], X1[8], Y0[8], Y1[8], a_cur, a_nxt;
    const short* blk = wpb;
    LOADG8(X0, blk, 0);
    LOADG8(X1, blk, 1);
    a_cur = *reinterpret_cast<const short8*>(Xrow);
#pragma unroll 1
    for (int kb = 0; kb < XB - 2; kb += 2) {
        LOADG8(Y0, blk + 8192, 0);
        LOADG8(Y1, blk + 8192, 1);
        a_nxt = *reinterpret_cast<const short8*>(Xrow + (kb + 1) * 32);
        MFMA8(a_cur, X0, 0);
        MFMA8(a_cur, X1, 1);
        a_cur = a_nxt;
        LOADG8(X0, blk + 2 * 8192, 0);
        LOADG8(X1, blk + 2 * 8192, 1);
        a_nxt = *reinterpret_cast<const short8*>(Xrow + (kb + 2) * 32);
        MFMA8(a_cur, Y0, 0);
        MFMA8(a_cur, Y1, 1);
        a_cur = a_nxt;
        blk += 2 * 8192;
    }
    LOADG8(Y0, blk + 8192, 0);
    LOADG8(Y1, blk + 8192, 1);
    a_nxt = *reinterpret_cast<const short8*>(Xrow + (XB - 1) * 32);
    MFMA8(a_cur, X0, 0);
    MFMA8(a_cur, X1, 1);
    a_cur = a_nxt;
    MFMA8(a_cur, Y0, 0);
    MFMA8(a_cur, Y1, 1);

    short* pb = Pre + ((((size_t)t * 2 + dir) * 64 + tile) << 14) + quad * 4;
#pragma unroll
    for (int g = 0; g < 4; ++g)
#pragma unroll
        for (int s = 0; s < 4; ++s) {
            short4v v;
#pragma unroll
            for (int r = 0; r < 4; ++r) v[r] = f2bf(acc[g * 4 + s][r]);
            *reinterpret_cast<short4v*>(pb + (g * 256 + p * 64 + s * 16 + lr) * 16) = v;
        }
}

// ---------------- recurrent LSTM (Whh-only, KB=8) --------------------------
__global__ __launch_bounds__(256, 1) void lstm_rec_kernel(
    const short* __restrict__ Wr,   // Whh blocked (repack_kernel XI=0)
    const float* __restrict__ bih, const float* __restrict__ bhh,
    const short* __restrict__ Pre,  // [t][dir][tile][j][m] bf16
    short* __restrict__ Hout)       // (62,1024,512); dir d -> cols [256d,..)
{
    const int wg    = blockIdx.x;   // 128
    const int dir   = wg >> 6;
    const int tile  = wg & 63;
    const int bbase = tile * 16;
    const int tid   = threadIdx.x;
    const int wv    = tid >> 6;
    const int lane  = tid & 63;
    const int quad  = lane >> 4;
    const int lr    = lane & 15;

    __shared__ __align__(16) short h_lds[16][264];
    __shared__ float bias_sh[1024];
    for (int i = tid; i < 16 * 264; i += 256) (&h_lds[0][0])[i] = 0;
    for (int i = tid; i < 1024; i += 256)
        bias_sh[i] = bih[dir * 1024 + i] + bhh[dir * 1024 + i];

    const short* wpb = Wr + (((size_t)(dir * 4 + wv) * 8) << 13) + lane * 8;

    float c_st[4][4];
#pragma unroll
    for (int s = 0; s < 4; ++s)
#pragma unroll
        for (int r = 0; r < 4; ++r) c_st[s][r] = 0.0f;

    __syncthreads();

    for (int st = 0; st < TSTEPS; ++st) {
        const int t = dir ? (TSTEPS - 1 - st) : st;

        // issue pre loads early; consumed only in the epilogue
        const short* pb = Pre + ((((size_t)t * 2 + dir) * 64 + tile) << 14) + quad * 4;
        short4v preg[16];
#pragma unroll
        for (int i = 0; i < 16; ++i)
            preg[i] = *reinterpret_cast<const short4v*>(
                pb + (((i >> 2) * 256) + wv * 64 + ((i & 3) * 16) + lr) * 16);

        floatx4 acc[16];
#pragma unroll
        for (int i = 0; i < 16; ++i) acc[i] = (floatx4){0.f, 0.f, 0.f, 0.f};

        short8 X0[8], X1[8], Y0[8], Y1[8], a_cur, a_nxt;
        const short* blk = wpb;
        LOADG8(X0, blk, 0);
        LOADG8(X1, blk, 1);
        a_cur = *reinterpret_cast<const short8*>(&h_lds[lr][quad * 8]);
#pragma unroll 1
        for (int kb = 0; kb < 6; kb += 2) {
            LOADG8(Y0, blk + 8192, 0);
            LOADG8(Y1, blk + 8192, 1);
            a_nxt = *reinterpret_cast<const short8*>(&h_lds[lr][(kb + 1) * 32 + quad * 8]);
            MFMA8(a_cur, X0, 0);
            MFMA8(a_cur, X1, 1);
            a_cur = a_nxt;
            LOADG8(X0, blk + 2 * 8192, 0);
            LOADG8(X1, blk + 2 * 8192, 1);
            a_nxt = *reinterpret_cast<const short8*>(&h_lds[lr][(kb + 2) * 32 + quad * 8]);
            MFMA8(a_cur, Y0, 0);
            MFMA8(a_cur, Y1, 1);
            a_cur = a_nxt;
            blk += 2 * 8192;
        }
        LOADG8(Y0, blk + 8192, 0);
        LOADG8(Y1, blk + 8192, 1);
        a_nxt = *reinterpret_cast<const short8*>(&h_lds[lr][7 * 32 + quad * 8]);
        MFMA8(a_cur, X0, 0);
        MFMA8(a_cur, X1, 1);
        a_cur = a_nxt;
        MFMA8(a_cur, Y0, 0);
        MFMA8(a_cur, Y1, 1);

        __syncthreads();  // all waves done reading h_lds

#pragma unroll
        for (int s = 0; s < 4; ++s) {
            int j = wv * 64 + s * 16 + lr;
            float bi  = bias_sh[0 * 256 + j];
            float bf  = bias_sh[1 * 256 + j];
            float bgv = bias_sh[2 * 256 + j];
            float bo  = bias_sh[3 * 256 + j];
#pragma unroll
            for (int r = 0; r < 4; ++r) {
                float iv = acc[0 * 4 + s][r] + bf2f(preg[0 * 4 + s][r]) + bi;
                float fv = acc[1 * 4 + s][r] + bf2f(preg[1 * 4 + s][r]) + bf;
                float gv = acc[2 * 4 + s][r] + bf2f(preg[2 * 4 + s][r]) + bgv;
                float ov = acc[3 * 4 + s][r] + bf2f(preg[3 * 4 + s][r]) + bo;
                float c = sigf(fv) * c_st[s][r] + sigf(iv) * tanhf_fast(gv);
                c_st[s][r] = c;
                float h = sigf(ov) * tanhf_fast(c);
                short hb = f2bf(h);
                int m = quad * 4 + r;
                h_lds[m][j] = hb;
                Hout[((size_t)t * BATCH + bbase + m) * 512 + dir * 256 + j] = hb;
            }
        }
        __syncthreads();
    }
}

// ---------------- fallback fused LSTM (round-8 proven) ---------------------
#define FLOADA(DST, kbg)                                                         \
    {                                                                            \
        DST = ((kbg) < XB)                                                       \
            ? *reinterpret_cast<const short8*>(Xrow + (kbg) * 32)                \
            : *reinterpret_cast<const short8*>(&h_lds[lr][((kbg) - XB) * 32 + quad * 8]); \
    }
template <int KK>  // 512 or 768
__global__ __launch_bounds__(256, 1) void lstm_fused_kernel(
    const short* __restrict__ X, const short* __restrict__ Wcat,
    const float* __restrict__ bih, const float* __restrict__ bhh,
    short* __restrict__ Hout)
{
    constexpr int XI = KK - 256;
    constexpr int KB = KK / 32;
    constexpr int XB = XI / 32;

    const int wg    = blockIdx.x;
    const int dir   = wg >> 6;
    const int bbase = (wg & 63) * 16;
    const int tid   = threadIdx.x;
    const int wv    = tid >> 6;
    const int lane  = tid & 63;
    const int quad  = lane >> 4;
    const int lr    = lane & 15;

    __shared__ __align__(16) short h_lds[16][264];
    __shared__ float bias_sh[1024];
    for (int i = tid; i < 16 * 264; i += 256) (&h_lds[0][0])[i] = 0;
    for (int i = tid; i < 1024; i += 256)
        bias_sh[i] = bih[dir * 1024 + i] + bhh[dir * 1024 + i];

    const short* wpb = Wcat + (((size_t)(dir * 4 + wv) * KB) << 13) + lane * 8;

    float c_st[4][4];
#pragma unroll
    for (int s = 0; s < 4; ++s)
#pragma unroll
        for (int r = 0; r < 4; ++r) c_st[s][r] = 0.0f;

    __syncthreads();

    for (int st = 0; st < TSTEPS; ++st) {
        const int t = dir ? (TSTEPS - 1 - st) : st;
        const short* Xrow = X + ((size_t)t * BATCH + bbase + lr) * XI + quad * 8;

        floatx4 acc[16];
#pragma unroll
        for (int i = 0; i < 16; ++i) acc[i] = (floatx4){0.f, 0.f, 0.f, 0.f};

        short8 X0[8], X1[8], Y0[8], Y1[8], a_cur, a_nxt;
        const short* blk = wpb;
        LOADG8(X0, blk, 0);
        LOADG8(X1, blk, 1);
        FLOADA(a_cur, 0);
#pragma unroll 1
        for (int kb = 0; kb < KB - 2; kb += 2) {
            LOADG8(Y0, blk + 8192, 0);
            LOADG8(Y1, blk + 8192, 1);
            FLOADA(a_nxt, kb + 1);
            MFMA8(a_cur, X0, 0);
            MFMA8(a_cur, X1, 1);
            a_cur = a_nxt;
            LOADG8(X0, blk + 2 * 8192, 0);
            LOADG8(X1, blk + 2 * 8192, 1);
            FLOADA(a_nxt, kb + 2);
            MFMA8(a_cur, Y0, 0);
            MFMA8(a_cur, Y1, 1);
            a_cur = a_nxt;
            blk += 2 * 8192;
        }
        LOADG8(Y0, blk + 8192, 0);
        LOADG8(Y1, blk + 8192, 1);
        FLOADA(a_nxt, KB - 1);
        MFMA8(a_cur, X0, 0);
        MFMA8(a_cur, X1, 1);
        a_cur = a_nxt;
        MFMA8(a_cur, Y0, 0);
        MFMA8(a_cur, Y1, 1);

        __syncthreads();

#pragma unroll
        for (int s = 0; s < 4; ++s) {
            int j = wv * 64 + s * 16 + lr;
            float bi  = bias_sh[0 * 256 + j];
            float bf  = bias_sh[1 * 256 + j];
            float bgv = bias_sh[2 * 256 + j];
            float bo  = bias_sh[3 * 256 + j];
#pragma unroll
            for (int r = 0; r < 4; ++r) {
                float iv = acc[0 * 4 + s][r] + bi;
                float fv = acc[1 * 4 + s][r] + bf;
                float gv = acc[2 * 4 + s][r] + bgv;
                float ov = acc[3 * 4 + s][r] + bo;
                float c = sigf(fv) * c_st[s][r] + sigf(iv) * tanhf_fast(gv);
                c_st[s][r] = c;
                float h = sigf(ov) * tanhf_fast(c);
                short hb = f2bf(h);
                int m = quad * 4 + r;
                h_lds[m][j] = hb;
                Hout[((size_t)t * BATCH + bbase + m) * 512 + dir * 256 + j] = hb;
            }
        }
        __syncthreads();
    }
}

// ---------------- heads (fp32 output) --------------------------------------
__global__ __launch_bounds__(256) void lout_kernel(
    const short* __restrict__ h1, const float* __restrict__ Wlp,
    const float* __restrict__ blp, float* __restrict__ out)
{
    __shared__ float wl[6 * 512];
    for (int i = threadIdx.x; i < 6 * 512; i += 256) wl[i] = Wlp[i];
    __syncthreads();

    int idx = blockIdx.x * 256 + threadIdx.x;
    if (idx >= BATCH * 60) return;
    int b = idx & (BATCH - 1);
    int s = idx >> 10;
    const short* hrow = h1 + ((size_t)(s + 1) * BATCH + b) * 512;

    float acc[6];
#pragma unroll
    for (int j = 0; j < 6; ++j) acc[j] = blp[j];
    for (int k = 0; k < 512; k += 8) {
        short8 hv = *reinterpret_cast<const short8*>(hrow + k);
#pragma unroll
        for (int e = 0; e < 8; ++e) {
            float h = bf2f(hv[e]);
#pragma unroll
            for (int j = 0; j < 6; ++j) acc[j] += h * wl[j * 512 + k + e];
        }
    }
    float* orow = out + ((size_t)b * 60 + s) * 14;
#pragma unroll
    for (int j = 0; j < 6; ++j) orow[j] = acc[j];
}

__global__ __launch_bounds__(256) void gout_kernel(
    const short* __restrict__ h1, const float* __restrict__ Wgp,
    const float* __restrict__ bgp, float* __restrict__ out)
{
    __shared__ float wg[8 * 1024];
    for (int i = threadIdx.x; i < 8 * 1024; i += 256) wg[i] = Wgp[i];
    __syncthreads();

    int b = blockIdx.x * 256 + threadIdx.x;
    if (b >= BATCH) return;
    const short* ha = h1 + (size_t)b * 512;
    const short* hb = h1 + ((size_t)61 * BATCH + b) * 512;

    float acc[8];
#pragma unroll
    for (int j = 0; j < 8; ++j) acc[j] = bgp[j];
    for (int k = 0; k < 512; k += 8) {
        short8 h1v = *reinterpret_cast<const short8*>(ha + k);
        short8 h2v = *reinterpret_cast<const short8*>(hb + k);
#pragma unroll
        for (int e = 0; e < 8; ++e) {
            float v1 = bf2f(h1v[e]);
            float v2 = bf2f(h2v[e]);
#pragma unroll
            for (int j = 0; j < 8; ++j) {
                acc[j] += v1 * wg[j * 1024 + k + e];
                acc[j] += v2 * wg[j * 1024 + 512 + k + e];
            }
        }
    }
    for (int s = 0; s < 60; ++s) {
        float* orow = out + ((size_t)b * 60 + s) * 14 + 6;
#pragma unroll
        for (int j = 0; j < 8; ++j) orow[j] = acc[j];
    }
}

// ---------------- launch ---------------------------------------------------
extern "C" void kernel_launch(void* const* d_in, const int* in_sizes, int n_in,
                              void* d_out, int out_size, void* d_ws, size_t ws_size,
                              hipStream_t stream)
{
    const float* x    = (const float*)d_in[0];
    const float* Wg   = (const float*)d_in[1];
    const float* bg   = (const float*)d_in[2];
    const float* Wl   = (const float*)d_in[3];
    const float* bl   = (const float*)d_in[4];
    const float* Wih0 = (const float*)d_in[5];
    const float* Whh0 = (const float*)d_in[6];
    const float* bih0 = (const float*)d_in[7];
    const float* bhh0 = (const float*)d_in[8];
    const float* Wih1 = (const float*)d_in[9];
    const float* Whh1 = (const float*)d_in[10];
    const float* bih1 = (const float*)d_in[11];
    const float* bhh1 = (const float*)d_in[12];
    const float* Wgp  = (const float*)d_in[13];
    const float* bgp  = (const float*)d_in[14];
    const float* Wlp  = (const float*)d_in[15];
    const float* blp  = (const float*)d_in[16];
    float* out = (float*)d_out;

    const size_t seq_e = (size_t)TSTEPS * BATCH * 256;   // 16,252,928
    const size_t h_e   = (size_t)TSTEPS * BATCH * 512;   // 32,505,856
    const size_t wr_e  = 8 * 8 * 8192;                   //   524,288 (Whh blocked)
    const size_t wa0_e = 8 * 8 * 8192;                   //   524,288 (Wih0 blocked)
    const size_t wa1_e = 8 * 16 * 8192;                  // 1,048,576 (Wih1 blocked)
    const size_t pre_e = (size_t)TSTEPS * 2 * 64 * 16384;// 130,023,424
    const size_t cat0_e = 8 * 16 * 8192;                 // fused fallback
    const size_t cat1_e = 8 * 24 * 8192;

    short* seq = (short*)d_ws;
    short* h0  = seq + seq_e;
    short* h1  = h0 + h_e;
    short* wb  = h1 + h_e;

    const size_t need_big = (seq_e + 2 * h_e + 2 * wr_e + wa0_e + wa1_e + pre_e) * 2;
    const size_t need_old = (seq_e + 2 * h_e + cat0_e + cat1_e) * 2;

    embed_kernel<<<BATCH, 256, 0, stream>>>(x, Wg, bg, Wl, bl, seq);

    if (ws_size >= need_big) {
        short* wr0 = wb;
        short* wr1 = wr0 + wr_e;
        short* wa0 = wr1 + wr_e;
        short* wa1 = wa0 + wa0_e;
        short* pre = wa1 + wa1_e;

        repack_kernel<<<(int)((wr_e + 255) / 256), 256, 0, stream>>>(Whh0, Whh0, wr0, 0);
        repack_kernel<<<(int)((wr_e + 255) / 256), 256, 0, stream>>>(Whh1, Whh1, wr1, 0);
        repack_a_kernel<<<(int)((wa0_e + 255) / 256), 256, 0, stream>>>(Wih0, wa0, 256);
        repack_a_kernel<<<(int)((wa1_e + 255) / 256), 256, 0, stream>>>(Wih1, wa1, 512);

        pre_gemm_kernel<256><<<TSTEPS * 128, 256, 0, stream>>>(seq, wa0, pre);
        lstm_rec_kernel<<<128, 256, 0, stream>>>(wr0, bih0, bhh0, pre, h0);
        pre_gemm_kernel<512><<<TSTEPS * 128, 256, 0, stream>>>(h0, wa1, pre);
        lstm_rec_kernel<<<128, 256, 0, stream>>>(wr1, bih1, bhh1, pre, h1);
    } else if (ws_size >= need_old) {
        short* wcat0 = wb;
        short* wcat1 = wcat0 + cat0_e;
        repack_kernel<<<(int)((cat0_e + 255) / 256), 256, 0, stream>>>(Wih0, Whh0, wcat0, 256);
        repack_kernel<<<(int)((cat1_e + 255) / 256), 256, 0, stream>>>(Wih1, Whh1, wcat1, 512);
        lstm_fused_kernel<512><<<128, 256, 0, stream>>>(seq, wcat0, bih0, bhh0, h0);
        lstm_fused_kernel<768><<<128, 256, 0, stream>>>(h0, wcat1, bih1, bhh1, h1);
    } else {
        return;
    }

    lout_kernel<<<(BATCH * 60 + 255) / 256, 256, 0, stream>>>(h1, Wlp, blp, out);
    gout_kernel<<<(BATCH + 255) / 256, 256, 0, stream>>>(h1, Wgp, bgp, out);
}

// Round 11
// 1652.008 us; speedup vs baseline: 1.4971x; 1.0982x over previous
//
#include <hip/hip_runtime.h>
#include <hip/hip_bf16.h>
#include <cstdint>
#include <cstddef>

// Model: B=1024, S=60, CIN=25, D=256, H=256, T=S+2=62
// Inputs fp32, output fp32; internal bf16 activations/weights, fp32 accum.
//
// Round-10 analysis: layer0==layer1 time (byte-insensitive) + ~2.8k cyc stall
// per k-iteration -> exposed HBM latency on the A-operand (X) loads and on the
// scattered per-lane Hout stores, NOT weight BW. Round 11 (minimal delta on
// the proven round-8 kernel):
//   (1) X[t+1] tile staged async into LDS double-buffer via global_load_lds
//       (row-wise: uniform LDS base + lane*16B) during step t -> A-loads are
//       LDS reads, HBM latency fully hidden. seq/h0 stored with +8-short row
//       padding (writers controlled) for conflict-free staged reads.
//   (2) h written to LDS only in the cell update; Hout written back after the
//       barrier as coalesced 16B stores (2/thread vs 16 scalar 2B stores).
//   (3) weight buffer shared between layers (repacked twice, stream-ordered)
//       to keep ws at 167.71 MB <= proven 167.77 MB.

typedef __attribute__((ext_vector_type(8))) short short8;
typedef __attribute__((ext_vector_type(4))) float floatx4;

#define BATCH 1024
#define TSTEPS 62

__device__ __forceinline__ float bf2f(short s) {
    union { unsigned u; float f; } v;
    v.u = ((unsigned)(unsigned short)s) << 16;
    return v.f;
}
__device__ __forceinline__ short f2bf(float f) {
    union { float f; unsigned u; } v; v.f = f;
    unsigned r = (v.u + 0x7fffu + ((v.u >> 16) & 1u)) >> 16;  // RNE
    return (short)r;
}
__device__ __forceinline__ float sigf(float x) {
    return __builtin_amdgcn_rcpf(1.0f + __expf(-x));
}
__device__ __forceinline__ float tanhf_fast(float x) {
    return 2.0f * __builtin_amdgcn_rcpf(1.0f + __expf(-2.0f * x)) - 1.0f;
}

// async 16B/lane global->LDS (LDS dest = uniform base + lane*16)
__device__ __forceinline__ void load_lds16(const short* g, short* l) {
    __builtin_amdgcn_global_load_lds(
        (const __attribute__((address_space(1))) void*)g,
        (__attribute__((address_space(3))) void*)l, 16, 0, 0);
}

// ------------- repack [Wih|Whh] into wave-blocked layout -------------------
// dst idx = ((((dr*4 + p)*KB + kb)*16 + gs)*64 + lane)*8 + j
__global__ __launch_bounds__(256) void repack_kernel(
    const float* __restrict__ Wih, const float* __restrict__ Whh,
    short* __restrict__ Wp, int XI)
{
    const int KB = (XI + 256) / 32;
    int idx = blockIdx.x * 256 + threadIdx.x;
    if (idx >= 8 * KB * 8192) return;
    int j    = idx & 7;
    int lane = (idx >> 3) & 63;
    int gs   = (idx >> 9) & 15;
    int rem  = idx >> 13;
    int kb   = rem % KB;
    int rem2 = rem / KB;
    int p    = rem2 & 3;
    int dr   = rem2 >> 2;
    int row  = (gs >> 2) * 256 + p * 64 + (gs & 3) * 16 + (lane & 15);
    int k    = kb * 32 + (lane >> 4) * 8 + j;
    float v = (k < XI) ? Wih[((size_t)dr * 1024 + row) * XI + k]
                       : Whh[((size_t)dr * 1024 + row) * 256 + (k - XI)];
    Wp[idx] = f2bf(v);
}

// ---------------- embed: seq[t][b][d], row stride 264 ----------------------
__global__ __launch_bounds__(256) void embed_kernel(
    const float* __restrict__ x, const float* __restrict__ Wg,
    const float* __restrict__ bg, const float* __restrict__ Wl,
    const float* __restrict__ bl, short* __restrict__ seq)
{
    const int b = blockIdx.x;
    const int d = threadIdx.x;  // 256 = D
    __shared__ float xs[1500];
    for (int i = d; i < 1500; i += 256) xs[i] = x[(size_t)b * 1500 + i];
    __syncthreads();

    float g = bg[d];
#pragma unroll
    for (int c = 0; c < 16; ++c) g += xs[9 + c] * Wg[d * 16 + c];
    short gb = f2bf(g);
    seq[((size_t)0 * BATCH + b) * 264 + d] = gb;
    seq[((size_t)61 * BATCH + b) * 264 + d] = gb;

    for (int t = 0; t < 60; ++t) {
        float v = bl[d];
#pragma unroll
        for (int c = 0; c < 9; ++c) v += xs[t * 25 + c] * Wl[d * 9 + c];
        seq[((size_t)(t + 1) * BATCH + b) * 264 + d] = f2bf(v);
    }
}

// ---------------- persistent biLSTM layer ----------------------------------
#define LOADG8(BUF, P, gh)                                                       \
    {                                                                            \
        _Pragma("unroll")                                                        \
        for (int f = 0; f < 8; ++f)                                              \
            BUF[f] = *reinterpret_cast<const short8*>((P) + ((gh) * 8 + f) * 512); \
    }
#define LOADA(DST, kbg)                                                          \
    {                                                                            \
        DST = ((kbg) < XB)                                                       \
            ? *reinterpret_cast<const short8*>(xs_cur + lr * (XI + 8) + (kbg) * 32 + quad * 8) \
            : *reinterpret_cast<const short8*>(&h_lds[lr][((kbg) - XB) * 32 + quad * 8]); \
    }
#define MFMA8(AV, BUF, gh)                                                       \
    {                                                                            \
        _Pragma("unroll")                                                        \
        for (int f = 0; f < 8; ++f)                                              \
            acc[(gh) * 8 + f] = __builtin_amdgcn_mfma_f32_16x16x32_bf16(         \
                AV, BUF[f], acc[(gh) * 8 + f], 0, 0, 0);                         \
    }
// stage one 16-row X tile (XI cols of XSTR-stride rows) into x_stage buffer
#define STAGE(BUFP, T1)                                                          \
    {                                                                            \
        const short* xtb = X + ((size_t)(T1) * BATCH + bbase) * XSTR;            \
        _Pragma("unroll")                                                        \
        for (int i = 0; i < 4; ++i) {                                            \
            int row = wv * 4 + i;                                                \
            if (XI == 512 || lane < 32)                                          \
                load_lds16(xtb + (size_t)row * XSTR + lane * 8,                  \
                           (BUFP) + row * (XI + 8));                             \
        }                                                                        \
    }

template <int KK, int XSTR, int OSTR>  // KK=512: XI=256 (layer0); KK=768: XI=512
__global__ __launch_bounds__(256, 1) void lstm_fused_kernel(
    const short* __restrict__ X,      // (62,1024,XSTR) bf16, first XI cols used
    const short* __restrict__ Wcat,   // wave-blocked [Wih|Whh]
    const float* __restrict__ bih, const float* __restrict__ bhh,
    short* __restrict__ Hout)         // (62,1024,OSTR); dir d -> cols [256d,..)
{
    constexpr int XI = KK - 256;
    constexpr int KB = KK / 32;   // 16 or 24 (even)
    constexpr int XB = XI / 32;

    const int wg    = blockIdx.x;     // 128 = 64 tiles x 2 dirs
    const int dir   = wg >> 6;
    const int bbase = (wg & 63) * 16;
    const int tid   = threadIdx.x;
    const int wv    = tid >> 6;
    const int lane  = tid & 63;
    const int quad  = lane >> 4;
    const int lr    = lane & 15;

    __shared__ __align__(16) short h_lds[16][264];
    __shared__ __align__(16) short x_stage[2][16 * (XI + 8)];
    __shared__ float bias_sh[1024];
    for (int i = tid; i < 16 * 264; i += 256) (&h_lds[0][0])[i] = 0;
    for (int i = tid; i < 1024; i += 256)
        bias_sh[i] = bih[dir * 1024 + i] + bhh[dir * 1024 + i];

    const short* wpb = Wcat + (((size_t)(dir * 4 + wv) * KB) << 13) + lane * 8;

    float c_st[4][4];
#pragma unroll
    for (int s = 0; s < 4; ++s)
#pragma unroll
        for (int r = 0; r < 4; ++r) c_st[s][r] = 0.0f;

    // prologue: stage X[t0] into buffer 0 (drained by the barrier below)
    {
        const int t0 = dir ? (TSTEPS - 1) : 0;
        STAGE(&x_stage[0][0], t0);
    }
    __syncthreads();

    for (int st = 0; st < TSTEPS; ++st) {
        const int t = dir ? (TSTEPS - 1 - st) : st;
        // stage next step's X tile into the other buffer (async, consumed
        // after this step's end barrier -> latency fully hidden)
        if (st + 1 < TSTEPS) {
            const int t1 = dir ? (TSTEPS - 2 - st) : (st + 1);
            STAGE(&x_stage[(st + 1) & 1][0], t1);
        }
        const short* xs_cur = &x_stage[st & 1][0];

        floatx4 acc[16];
#pragma unroll
        for (int i = 0; i < 16; ++i) acc[i] = (floatx4){0.f, 0.f, 0.f, 0.f};

        // distance-2 weight pipeline (proven round-8 structure)
        short8 X0[8], X1[8], Y0[8], Y1[8], a_cur, a_nxt;
        const short* blk = wpb;
        LOADG8(X0, blk, 0);
        LOADG8(X1, blk, 1);
        LOADA(a_cur, 0);
#pragma unroll 1
        for (int kb = 0; kb < KB - 2; kb += 2) {
            LOADG8(Y0, blk + 8192, 0);
            LOADG8(Y1, blk + 8192, 1);
            LOADA(a_nxt, kb + 1);
            MFMA8(a_cur, X0, 0);
            MFMA8(a_cur, X1, 1);
            a_cur = a_nxt;
            LOADG8(X0, blk + 2 * 8192, 0);
            LOADG8(X1, blk + 2 * 8192, 1);
            LOADA(a_nxt, kb + 2);
            MFMA8(a_cur, Y0, 0);
            MFMA8(a_cur, Y1, 1);
            a_cur = a_nxt;
            blk += 2 * 8192;
        }
        LOADG8(Y0, blk + 8192, 0);
        LOADG8(Y1, blk + 8192, 1);
        LOADA(a_nxt, KB - 1);
        MFMA8(a_cur, X0, 0);
        MFMA8(a_cur, X1, 1);
        a_cur = a_nxt;
        MFMA8(a_cur, Y0, 0);
        MFMA8(a_cur, Y1, 1);

        __syncthreads();  // all waves done reading h_lds (and staged X)

        // cell update -> h_lds only (no scattered global stores)
#pragma unroll
        for (int s = 0; s < 4; ++s) {
            int j = wv * 64 + s * 16 + lr;
            float bi  = bias_sh[0 * 256 + j];
            float bf  = bias_sh[1 * 256 + j];
            float bgv = bias_sh[2 * 256 + j];
            float bo  = bias_sh[3 * 256 + j];
#pragma unroll
            for (int r = 0; r < 4; ++r) {
                float iv = acc[0 * 4 + s][r] + bi;
                float fv = acc[1 * 4 + s][r] + bf;
                float gv = acc[2 * 4 + s][r] + bgv;
                float ov = acc[3 * 4 + s][r] + bo;
                float c = sigf(fv) * c_st[s][r] + sigf(iv) * tanhf_fast(gv);
                c_st[s][r] = c;
                float h = sigf(ov) * tanhf_fast(c);
                h_lds[quad * 4 + r][j] = f2bf(h);
            }
        }
        __syncthreads();  // h complete

        // vectorized Hout writeback: 16B x2 per thread, coalesced; stores
        // drain during the NEXT step (no exposed ack latency)
        {
            int row = tid >> 4, cg = tid & 15;
            short8 v0 = *reinterpret_cast<const short8*>(&h_lds[row][cg * 16]);
            short8 v1 = *reinterpret_cast<const short8*>(&h_lds[row][cg * 16 + 8]);
            short* orow = Hout + ((size_t)t * BATCH + bbase + row) * OSTR +
                          dir * 256 + cg * 16;
            *reinterpret_cast<short8*>(orow) = v0;
            *reinterpret_cast<short8*>(orow + 8) = v1;
        }
    }
}

// ---------------- heads (fp32 output; h1 row stride 512) -------------------
__global__ __launch_bounds__(256) void lout_kernel(
    const short* __restrict__ h1, const float* __restrict__ Wlp,
    const float* __restrict__ blp, float* __restrict__ out)
{
    __shared__ float wl[6 * 512];
    for (int i = threadIdx.x; i < 6 * 512; i += 256) wl[i] = Wlp[i];
    __syncthreads();

    int idx = blockIdx.x * 256 + threadIdx.x;
    if (idx >= BATCH * 60) return;
    int b = idx & (BATCH - 1);
    int s = idx >> 10;
    const short* hrow = h1 + ((size_t)(s + 1) * BATCH + b) * 512;

    float acc[6];
#pragma unroll
    for (int j = 0; j < 6; ++j) acc[j] = blp[j];
    for (int k = 0; k < 512; k += 8) {
        short8 hv = *reinterpret_cast<const short8*>(hrow + k);
#pragma unroll
        for (int e = 0; e < 8; ++e) {
            float h = bf2f(hv[e]);
#pragma unroll
            for (int j = 0; j < 6; ++j) acc[j] += h * wl[j * 512 + k + e];
        }
    }
    float* orow = out + ((size_t)b * 60 + s) * 14;
#pragma unroll
    for (int j = 0; j < 6; ++j) orow[j] = acc[j];
}

__global__ __launch_bounds__(256) void gout_kernel(
    const short* __restrict__ h1, const float* __restrict__ Wgp,
    const float* __restrict__ bgp, float* __restrict__ out)
{
    __shared__ float wg[8 * 1024];
    for (int i = threadIdx.x; i < 8 * 1024; i += 256) wg[i] = Wgp[i];
    __syncthreads();

    int b = blockIdx.x * 256 + threadIdx.x;
    if (b >= BATCH) return;
    const short* ha = h1 + (size_t)b * 512;
    const short* hb = h1 + ((size_t)61 * BATCH + b) * 512;

    float acc[8];
#pragma unroll
    for (int j = 0; j < 8; ++j) acc[j] = bgp[j];
    for (int k = 0; k < 512; k += 8) {
        short8 h1v = *reinterpret_cast<const short8*>(ha + k);
        short8 h2v = *reinterpret_cast<const short8*>(hb + k);
#pragma unroll
        for (int e = 0; e < 8; ++e) {
            float v1 = bf2f(h1v[e]);
            float v2 = bf2f(h2v[e]);
#pragma unroll
            for (int j = 0; j < 8; ++j) {
                acc[j] += v1 * wg[j * 1024 + k + e];
                acc[j] += v2 * wg[j * 1024 + 512 + k + e];
            }
        }
    }
    for (int s = 0; s < 60; ++s) {
        float* orow = out + ((size_t)b * 60 + s) * 14 + 6;
#pragma unroll
        for (int j = 0; j < 8; ++j) orow[j] = acc[j];
    }
}

// ---------------- launch ---------------------------------------------------
extern "C" void kernel_launch(void* const* d_in, const int* in_sizes, int n_in,
                              void* d_out, int out_size, void* d_ws, size_t ws_size,
                              hipStream_t stream)
{
    const float* x    = (const float*)d_in[0];
    const float* Wg   = (const float*)d_in[1];
    const float* bg   = (const float*)d_in[2];
    const float* Wl   = (const float*)d_in[3];
    const float* bl   = (const float*)d_in[4];
    const float* Wih0 = (const float*)d_in[5];
    const float* Whh0 = (const float*)d_in[6];
    const float* bih0 = (const float*)d_in[7];
    const float* bhh0 = (const float*)d_in[8];
    const float* Wih1 = (const float*)d_in[9];
    const float* Whh1 = (const float*)d_in[10];
    const float* bih1 = (const float*)d_in[11];
    const float* bhh1 = (const float*)d_in[12];
    const float* Wgp  = (const float*)d_in[13];
    const float* bgp  = (const float*)d_in[14];
    const float* Wlp  = (const float*)d_in[15];
    const float* blp  = (const float*)d_in[16];
    float* out = (float*)d_out;

    const size_t seq_e = (size_t)TSTEPS * BATCH * 264;  // 16,760,832 (stride 264)
    const size_t h0_e  = (size_t)TSTEPS * BATCH * 520;  // 33,013,760 (stride 520)
    const size_t h1_e  = (size_t)TSTEPS * BATCH * 512;  // 32,505,856 (stride 512)
    const size_t cat_e = 8 * 24 * 8192;                 //  1,572,864 (shared, max)
    const size_t cat0_n = 8 * 16 * 8192;                //  layer0 repack count

    short* seq = (short*)d_ws;
    short* h0  = seq + seq_e;
    short* h1  = h0 + h0_e;
    short* cat = h1 + h1_e;
    const size_t need = (seq_e + h0_e + h1_e + cat_e) * sizeof(short);  // 167.71 MB
    if (ws_size < need) return;

    embed_kernel<<<BATCH, 256, 0, stream>>>(x, Wg, bg, Wl, bl, seq);

    repack_kernel<<<(int)((cat0_n + 255) / 256), 256, 0, stream>>>(Wih0, Whh0, cat, 256);
    lstm_fused_kernel<512, 264, 520><<<128, 256, 0, stream>>>(seq, cat, bih0, bhh0, h0);

    repack_kernel<<<(int)((cat_e + 255) / 256), 256, 0, stream>>>(Wih1, Whh1, cat, 512);
    lstm_fused_kernel<768, 520, 512><<<128, 256, 0, stream>>>(h0, cat, bih1, bhh1, h1);

    lout_kernel<<<(BATCH * 60 + 255) / 256, 256, 0, stream>>>(h1, Wlp, blp, out);
    gout_kernel<<<(BATCH + 255) / 256, 256, 0, stream>>>(h1, Wgp, bgp, out);
}